// Round 9
// baseline (378.853 us; speedup 1.0000x reference)
//
#include <hip/hip_runtime.h>
#include <hip/hip_bf16.h>

// Problem constants (SpatialGraphConvolution_21251498180686)
#define NN 10000      // nodes per graph
#define EE 320000     // edges (before self-loops)
#define BB 4          // batch (graphs share edge structure)
#define F0 256        // input feat
#define F1 256        // hidden feat
#define F2 128        // output feat
#define ETOT (EE + NN)

typedef __attribute__((ext_vector_type(8))) short bf16x8;
typedef __attribute__((ext_vector_type(4))) float f32x4;

__device__ inline unsigned short f2bf_rn(float f) {
    unsigned int u = __float_as_uint(f);
    unsigned int r = (u + 0x7fffu + ((u >> 16) & 1u)) >> 16;
    return (unsigned short)r;
}
__device__ inline float bf2f(unsigned short s) {
    return __uint_as_float(((unsigned int)s) << 16);
}

// async 16B global -> LDS (direct-to-shared DMA, vmcnt-tracked)
__device__ __forceinline__ void gload16(const void* g, void* lds) {
    __builtin_amdgcn_global_load_lds(
        (const __attribute__((address_space(1))) unsigned int*)g,
        (__attribute__((address_space(3))) unsigned int*)lds, 16, 0, 0);
}

// ---------------------------------------------------------------------------
// CSR build (by dst) — int inputs arrive as int32.
// ---------------------------------------------------------------------------
__global__ void count_kernel(const int* __restrict__ ei, int* __restrict__ deg) {
    int id = blockIdx.x * blockDim.x + threadIdx.x;
    if (id >= ETOT) return;
    int dst = (id < EE) ? ei[EE + id] : (id - EE);
    atomicAdd(&deg[dst], 1);
}

__global__ void scan_kernel(const int* __restrict__ deg, int* __restrict__ rowstart) {
    __shared__ int part[256];
    int t = threadIdx.x;
    const int CH = (NN + 255) / 256;  // 40
    int lo = t * CH, hi = min(lo + CH, NN);
    int s = 0;
    for (int i = lo; i < hi; i++) s += deg[i];
    part[t] = s;
    __syncthreads();
    for (int off = 1; off < 256; off <<= 1) {
        int v = (t >= off) ? part[t - off] : 0;
        __syncthreads();
        part[t] += v;
        __syncthreads();
    }
    int run = (t == 0) ? 0 : part[t - 1];
    for (int i = lo; i < hi; i++) { int d = deg[i]; rowstart[i] = run; run += d; }
    if (t == 255) rowstart[NN] = run;
}

__global__ void scatter_kernel(const int* __restrict__ ei,
                               const int* __restrict__ rowstart,
                               int* __restrict__ fill,
                               int* __restrict__ sorted_src) {
    int id = blockIdx.x * blockDim.x + threadIdx.x;
    if (id >= ETOT) return;
    int src, dst;
    if (id < EE) { src = ei[id]; dst = ei[EE + id]; }
    else         { src = dst = id - EE; }
    int pos = rowstart[dst] + atomicAdd(&fill[dst], 1);
    sorted_src[pos] = src;
}

// ---------------------------------------------------------------------------
// Split a fp32 matrix into [hi | lo] bf16 halves: out2[r][0..K)=hi, [K..2K)=lo.
// ---------------------------------------------------------------------------
__global__ __launch_bounds__(256) void conv_split(const float* __restrict__ in,
                                                  unsigned short* __restrict__ out2,
                                                  int rows, int K) {
    int q = K >> 2;
    int id = blockIdx.x * blockDim.x + threadIdx.x;
    if (id >= rows * q) return;
    int r = id / q;
    int c4 = (id - r * q) << 2;
    float4 v = *(const float4*)(in + (size_t)r * K + c4);
    ushort4 hi, lo;
    hi.x = f2bf_rn(v.x); lo.x = f2bf_rn(v.x - bf2f(hi.x));
    hi.y = f2bf_rn(v.y); lo.y = f2bf_rn(v.y - bf2f(hi.y));
    hi.z = f2bf_rn(v.z); lo.z = f2bf_rn(v.z - bf2f(hi.z));
    hi.w = f2bf_rn(v.w); lo.w = f2bf_rn(v.w - bf2f(hi.w));
    unsigned short* o = out2 + (size_t)r * 2 * K;
    *(ushort4*)(o + c4) = hi;
    *(ushort4*)(o + K + c4) = lo;
}

// ---------------------------------------------------------------------------
// Skinny split-bf16 MFMA GEMM + fused al epilogue.  (R9: single-stage A)
// C[M,NC] bf16 = A[M,256] * B[NC,256]^T, 3 split terms via
// phase0: A-hi x (B-hi + B-lo), phase1: A-lo x B-hi.
// M-tile = 32, block covers all NC cols -> 1250 blocks (5 blocks/CU).
//
// R8 post-mortem: per-chunk gload16+__syncthreads drained full L3 latency
// (~700cyc) 16x per block -> MfmaUtil 8%. R9: stage the WHOLE 32x512-short
// A-block (32KB) in one burst of 8 DMAs + ONE barrier; then 192 MFMAs with
// no barriers — B direct-from-global loads pipeline freely across the loop.
// XOR-swizzled staging (R8-proven, SQ_LDS_BANK_CONFLICT=0): LDS unit
// (row,u) holds global unit (row, u^(row&7)).
// ---------------------------------------------------------------------------
template <int NC>
__global__ __launch_bounds__(256) void gemm_skinny(
    const unsigned short* __restrict__ A2,   // [M][512]  ([hi|lo] per row)
    const unsigned short* __restrict__ B2,   // [NC][512]
    unsigned short* __restrict__ C,          // [M][NC] bf16
    const float* __restrict__ asrc,
    const float* __restrict__ adst,
    float* __restrict__ als,
    float* __restrict__ ald) {
    constexpr int JT = NC / 64;              // j-tiles per wave (4 or 2)
    constexpr int CP = NC + 8;               // padded Cs pitch (shorts)
    __shared__ unsigned short sbuf[32 * 512];  // As 32KB; epilogue Cs[32][CP] aliases
    unsigned short* As = sbuf;
    int tid = threadIdx.x;
    int wave = tid >> 6, lane = tid & 63;
    int lq = lane >> 4, lm = lane & 15;
    int bm = blockIdx.x * 32;

    f32x4 acc[2][JT];
#pragma unroll
    for (int i = 0; i < 2; i++)
#pragma unroll
        for (int j = 0; j < JT; j++) {
            acc[i][j][0] = 0.f; acc[i][j][1] = 0.f;
            acc[i][j][2] = 0.f; acc[i][j][3] = 0.f;
        }

    // ---- single-burst A staging: 8 DMAs/thread, one barrier ----
    // LDS unit L = r*256+tid -> (row L>>6, unit L&63) holds global unit ((L&63)^(row&7))
#pragma unroll
    for (int r = 0; r < 8; r++) {
        int L = r * 256 + tid;
        int lrow = L >> 6;
        int guir = (L & 63) ^ (lrow & 7);
        gload16(A2 + (size_t)(bm + lrow) * 512 + (guir << 3), As + L * 8);
    }

    // B fragment row pointers (direct global; bypasses LDS entirely)
    const unsigned short* bRow[JT];
#pragma unroll
    for (int j = 0; j < JT; j++)
        bRow[j] = B2 + (size_t)(wave * (NC / 4) + j * 16 + lm) * 512 + lq * 8;

    __syncthreads();   // drains the 8 DMAs (once per block)

    // ---- MFMA loop: no barriers, loads pipeline freely ----
    int lx = lm & 7;
#pragma unroll
    for (int ph = 0; ph < 2; ph++) {
#pragma unroll 2
        for (int kk = 0; kk < 8; kk++) {
            int ku = ph * 32 + kk * 4 + lq;      // A k-unit (8 shorts)
            const unsigned short* ap = As + lm * 512 + ((ku ^ lx) << 3);
            bf16x8 af0 = *(const bf16x8*)(ap);
            bf16x8 af1 = *(const bf16x8*)(ap + 16 * 512);
#pragma unroll
            for (int j = 0; j < JT; j++) {
                bf16x8 bh = *(const bf16x8*)(bRow[j] + kk * 32);
                acc[0][j] = __builtin_amdgcn_mfma_f32_16x16x32_bf16(af0, bh, acc[0][j], 0, 0, 0);
                acc[1][j] = __builtin_amdgcn_mfma_f32_16x16x32_bf16(af1, bh, acc[1][j], 0, 0, 0);
            }
            if (ph == 0) {
#pragma unroll
                for (int j = 0; j < JT; j++) {
                    bf16x8 bl = *(const bf16x8*)(bRow[j] + 256 + kk * 32);
                    acc[0][j] = __builtin_amdgcn_mfma_f32_16x16x32_bf16(af0, bl, acc[0][j], 0, 0, 0);
                    acc[1][j] = __builtin_amdgcn_mfma_f32_16x16x32_bf16(af1, bl, acc[1][j], 0, 0, 0);
                }
            }
        }
    }

    __syncthreads();   // all As reads done; Cs aliases sbuf

    // Epilogue. C/D layout: col = lane&15, row = (lane>>4)*4 + reg.
    unsigned short* Cs = sbuf;  // [32][CP]
#pragma unroll
    for (int i = 0; i < 2; i++)
#pragma unroll
        for (int rr = 0; rr < 4; rr++) {
            int row = i * 16 + lq * 4 + rr;
#pragma unroll
            for (int j = 0; j < JT; j++)
                Cs[row * CP + wave * (NC / 4) + j * 16 + lm] = f2bf_rn(acc[i][j][rr]);
        }
    __syncthreads();

    // fused al: 8 threads per row, each covers NC/8 cols
    {
        int r = tid >> 3;
        int cseg = (tid & 7) * (NC / 8);
        float s = 0.f, d = 0.f;
#pragma unroll
        for (int c8 = 0; c8 < NC / 64; c8++) {
            bf16x8 v8 = *(const bf16x8*)(Cs + r * CP + cseg + c8 * 8);
#pragma unroll
            for (int u = 0; u < 8; u++) {
                float v = bf2f((unsigned short)v8[u]);
                s += v * asrc[cseg + c8 * 8 + u];
                d += v * adst[cseg + c8 * 8 + u];
            }
        }
        s += __shfl_xor(s, 1); d += __shfl_xor(d, 1);
        s += __shfl_xor(s, 2); d += __shfl_xor(d, 2);
        s += __shfl_xor(s, 4); d += __shfl_xor(d, 4);
        if ((tid & 7) == 0) { als[bm + r] = s; ald[bm + r] = d; }
    }

    // coalesced C store (32 rows x NC/8 uint4 units)
#pragma unroll
    for (int u0 = 0; u0 < NC / 64; u0++) {
        int u = u0 * 256 + tid;
        int row = u / (NC / 8), q = u % (NC / 8);
        *(uint4*)(C + (size_t)(bm + row) * NC + q * 8) = *(const uint4*)(Cs + row * CP + q * 8);
    }
}

// ---------------------------------------------------------------------------
// Fused attention softmax + aggregate + bias + relu (bf16 h gather).
// One wave per (graph b, dst node n); 16-wide load bursts for MLP.
// XCD-pinned: blockIdx&7 -> XCD; graph b = (blockIdx&7)>>1 gets XCD pair.
// OUTMODE 0: fp32 out.  OUTMODE 1: split-bf16 [M][2F] feeding next GEMM.
// ---------------------------------------------------------------------------
template <int F, int OUTMODE>
__global__ __launch_bounds__(256) void agg_kernel(const unsigned short* __restrict__ h,
                                                  const float* __restrict__ als,
                                                  const float* __restrict__ ald,
                                                  const int* __restrict__ rowstart,
                                                  const int* __restrict__ sorted_src,
                                                  const float* __restrict__ bias,
                                                  float* __restrict__ out,
                                                  unsigned short* __restrict__ out2) {
    constexpr int V = F / 64;
    typedef unsigned short usv __attribute__((ext_vector_type(V)));
    typedef float fvec __attribute__((ext_vector_type(V)));

    int bx = blockIdx.x;
    int xcd = bx & 7;
    int b = xcd >> 1;                              // graph
    int ng = ((bx >> 3) << 1) | (xcd & 1);         // node group 0..2499
    int n = ng * 4 + (threadIdx.x >> 6);           // node
    int lane = threadIdx.x & 63;
    int wid = b * NN + n;

    const float* als_b = als + (size_t)b * NN;
    float aldn = ald[wid];
    int rs = rowstart[n];
    int deg = rowstart[n + 1] - rs;
    const unsigned short* hb = h + (size_t)b * NN * F;

    fvec acc;
#pragma unroll
    for (int u = 0; u < V; u++) acc[u] = 0.f;
    float sum = 0.f;

    for (int c0 = 0; c0 < deg; c0 += 64) {
        int j = c0 + lane;
        float ex = 0.f;
        int srcj = 0;
        if (j < deg) {
            srcj = sorted_src[rs + j];
            float e = als_b[srcj] + aldn;
            e = e > 0.f ? e : 0.2f * e;
            ex = __expf(e);
        }
        sum += ex;
        int cnt = min(64, deg - c0);

        int nfull = cnt >> 4;
        for (int g = 0; g < nfull; g++) {
            int bse = g << 4;
            int s[16]; float w[16];
#pragma unroll
            for (int i = 0; i < 16; i++) {
                s[i] = __shfl(srcj, bse + i);
                w[i] = __shfl(ex, bse + i);
            }
            usv r[16];
#pragma unroll
            for (int i = 0; i < 16; i++)
                r[i] = *(const usv*)(hb + (size_t)s[i] * F + lane * V);
#pragma unroll
            for (int i = 0; i < 16; i++)
#pragma unroll
                for (int u = 0; u < V; u++) acc[u] += w[i] * bf2f(r[i][u]);
        }
        for (int bse = nfull << 4; bse < cnt; bse += 4) {
            int s[4]; float w[4];
#pragma unroll
            for (int i = 0; i < 4; i++) {
                s[i] = __shfl(srcj, bse + i);
                w[i] = __shfl(ex, bse + i);
            }
            usv r[4];
#pragma unroll
            for (int i = 0; i < 4; i++)
                r[i] = *(const usv*)(hb + (size_t)s[i] * F + lane * V);
#pragma unroll
            for (int i = 0; i < 4; i++)
#pragma unroll
                for (int u = 0; u < V; u++) acc[u] += w[i] * bf2f(r[i][u]);
        }
    }
#pragma unroll
    for (int off = 32; off; off >>= 1) sum += __shfl_xor(sum, off);
    float inv = 1.0f / (sum + 1e-16f);

    fvec r;
#pragma unroll
    for (int u = 0; u < V; u++) {
        float v = acc[u] * inv + bias[lane * V + u];
        r[u] = fmaxf(v, 0.f);
    }
    if (OUTMODE == 0) {
        *(fvec*)(out + (size_t)wid * F + lane * V) = r;
    } else {
        ushort4 hi, lo;
        hi.x = f2bf_rn(r[0]); lo.x = f2bf_rn(r[0] - bf2f(hi.x));
        hi.y = f2bf_rn(r[1]); lo.y = f2bf_rn(r[1] - bf2f(hi.y));
        hi.z = f2bf_rn(r[2]); lo.z = f2bf_rn(r[2] - bf2f(hi.z));
        hi.w = f2bf_rn(r[3]); lo.w = f2bf_rn(r[3] - bf2f(hi.w));
        unsigned short* o = out2 + (size_t)wid * 2 * F;
        *(ushort4*)(o + lane * 4) = hi;
        *(ushort4*)(o + F + lane * 4) = lo;
    }
}

// ---------------------------------------------------------------------------
extern "C" void kernel_launch(void* const* d_in, const int* in_sizes, int n_in,
                              void* d_out, int out_size, void* d_ws, size_t ws_size,
                              hipStream_t stream) {
    const float* x     = (const float*)d_in[0];
    const int*   ei    = (const int*)d_in[1];
    const float* W0    = (const float*)d_in[2];
    const float* b0    = (const float*)d_in[3];
    const float* asrc0 = (const float*)d_in[4];
    const float* adst0 = (const float*)d_in[5];
    const float* W1    = (const float*)d_in[6];
    const float* b1    = (const float*)d_in[7];
    const float* asrc1 = (const float*)d_in[8];
    const float* adst1 = (const float*)d_in[9];
    float* outp = (float*)d_out;

    const int M = BB * NN;  // 40000

    size_t off = 0;
    char* base = (char*)d_ws;
    auto alloc = [&](size_t bytes) {
        void* p = base + off;
        off += (bytes + 255) & ~(size_t)255;
        return p;
    };
    int*   deg        = (int*)alloc((size_t)NN * 4);   // deg+fill zeroed in ONE memset
    int*   fill       = (int*)alloc((size_t)NN * 4);
    int*   rowstart   = (int*)alloc((size_t)(NN + 1) * 4);
    int*   sorted_src = (int*)alloc((size_t)ETOT * 4);
    unsigned short* A2  = (unsigned short*)alloc((size_t)M * 512 * 2);  // x-split; reused as out0-split
    unsigned short* W02 = (unsigned short*)alloc((size_t)F1 * 512 * 2);
    unsigned short* W12 = (unsigned short*)alloc((size_t)F2 * 512 * 2);
    unsigned short* h   = (unsigned short*)alloc((size_t)M * F1 * 2);   // bf16 pre-agg features
    float* als        = (float*)alloc((size_t)M * 4);
    float* ald        = (float*)alloc((size_t)M * 4);

    hipMemsetAsync(deg, 0, (char*)fill - (char*)deg + (size_t)NN * 4, stream);

    int egrid = (ETOT + 255) / 256;
    count_kernel<<<egrid, 256, 0, stream>>>(ei, deg);
    scan_kernel<<<1, 256, 0, stream>>>(deg, rowstart);
    scatter_kernel<<<egrid, 256, 0, stream>>>(ei, rowstart, fill, sorted_src);

    int wgrid = (M * 64) / 256;            // 10000 blocks, 1 wave per (b,node)

    conv_split<<<(M * (F0 / 4) + 255) / 256, 256, 0, stream>>>(x, A2, M, F0);
    conv_split<<<(F1 * (F0 / 4) + 255) / 256, 256, 0, stream>>>(W0, W02, F1, F0);
    conv_split<<<(F2 * (F1 / 4) + 255) / 256, 256, 0, stream>>>(W1, W12, F2, F1);

    // ----- layer 0 -----  (al fused into GEMM epilogue)
    gemm_skinny<F1><<<M / 32, 256, 0, stream>>>(A2, W02, h, asrc0, adst0, als, ald);
    agg_kernel<F1, 1><<<wgrid, 256, 0, stream>>>(h, als, ald, rowstart, sorted_src, b0,
                                                 nullptr, A2 /* out0 split */);

    // ----- layer 1 -----
    gemm_skinny<F2><<<M / 32, 256, 0, stream>>>(A2, W12, h, asrc1, adst1, als, ald);
    agg_kernel<F2, 0><<<wgrid, 256, 0, stream>>>(h, als, ald, rowstart, sorted_src, b1,
                                                 outp, nullptr);
}

// Round 10
// 322.904 us; speedup vs baseline: 1.1733x; 1.1733x over previous
//
#include <hip/hip_runtime.h>
#include <hip/hip_bf16.h>

// Problem constants (SpatialGraphConvolution_21251498180686)
#define NN 10000      // nodes per graph
#define EE 320000     // edges (before self-loops)
#define BB 4          // batch (graphs share edge structure)
#define F0 256        // input feat
#define F1 256        // hidden feat
#define F2 128        // output feat
#define ETOT (EE + NN)

typedef __attribute__((ext_vector_type(8))) short bf16x8;
typedef __attribute__((ext_vector_type(4))) float f32x4;

__device__ inline unsigned short f2bf_rn(float f) {
    unsigned int u = __float_as_uint(f);
    unsigned int r = (u + 0x7fffu + ((u >> 16) & 1u)) >> 16;
    return (unsigned short)r;
}
__device__ inline float bf2f(unsigned short s) {
    return __uint_as_float(((unsigned int)s) << 16);
}

// ---------------------------------------------------------------------------
// CSR build (by dst) — int inputs arrive as int32.
// ---------------------------------------------------------------------------
__global__ void count_kernel(const int* __restrict__ ei, int* __restrict__ deg) {
    int id = blockIdx.x * blockDim.x + threadIdx.x;
    if (id >= ETOT) return;
    int dst = (id < EE) ? ei[EE + id] : (id - EE);
    atomicAdd(&deg[dst], 1);
}

__global__ void scan_kernel(const int* __restrict__ deg, int* __restrict__ rowstart) {
    __shared__ int part[256];
    int t = threadIdx.x;
    const int CH = (NN + 255) / 256;  // 40
    int lo = t * CH, hi = min(lo + CH, NN);
    int s = 0;
    for (int i = lo; i < hi; i++) s += deg[i];
    part[t] = s;
    __syncthreads();
    for (int off = 1; off < 256; off <<= 1) {
        int v = (t >= off) ? part[t - off] : 0;
        __syncthreads();
        part[t] += v;
        __syncthreads();
    }
    int run = (t == 0) ? 0 : part[t - 1];
    for (int i = lo; i < hi; i++) { int d = deg[i]; rowstart[i] = run; run += d; }
    if (t == 255) rowstart[NN] = run;
}

__global__ void scatter_kernel(const int* __restrict__ ei,
                               const int* __restrict__ rowstart,
                               int* __restrict__ fill,
                               int* __restrict__ sorted_src) {
    int id = blockIdx.x * blockDim.x + threadIdx.x;
    if (id >= ETOT) return;
    int src, dst;
    if (id < EE) { src = ei[id]; dst = ei[EE + id]; }
    else         { src = dst = id - EE; }
    int pos = rowstart[dst] + atomicAdd(&fill[dst], 1);
    sorted_src[pos] = src;
}

// ---------------------------------------------------------------------------
// Split a fp32 matrix into [hi | lo] bf16 halves: out2[r][0..K)=hi, [K..2K)=lo.
// ---------------------------------------------------------------------------
__global__ __launch_bounds__(256) void conv_split(const float* __restrict__ in,
                                                  unsigned short* __restrict__ out2,
                                                  int rows, int K) {
    int q = K >> 2;
    int id = blockIdx.x * blockDim.x + threadIdx.x;
    if (id >= rows * q) return;
    int r = id / q;
    int c4 = (id - r * q) << 2;
    float4 v = *(const float4*)(in + (size_t)r * K + c4);
    ushort4 hi, lo;
    hi.x = f2bf_rn(v.x); lo.x = f2bf_rn(v.x - bf2f(hi.x));
    hi.y = f2bf_rn(v.y); lo.y = f2bf_rn(v.y - bf2f(hi.y));
    hi.z = f2bf_rn(v.z); lo.z = f2bf_rn(v.z - bf2f(hi.z));
    hi.w = f2bf_rn(v.w); lo.w = f2bf_rn(v.w - bf2f(hi.w));
    unsigned short* o = out2 + (size_t)r * 2 * K;
    *(ushort4*)(o + c4) = hi;
    *(ushort4*)(o + K + c4) = lo;
}

// ---------------------------------------------------------------------------
// R10 GEMM: register-prefetch double-buffered split-bf16 MFMA GEMM,
// A read ONCE: per 32-k chunk stage Ah/Al/Bh/Bl tiles (128x32 each, pitch 40)
// and run all 3 split terms (Ah*Bh + Al*Bh + Ah*Bl) = 48 MFMA/wave/chunk.
// Pipeline per chunk: barrier; ds_write regs(c); barrier; issue global loads
// for c+1 (fly during MFMA); MFMA(c). The barrier never waits a cold load.
// Tile 128x128, 4 waves (2x2 of 64x64). 8 chunks (K=256).
// Epilogue: Cs in LDS -> fused partial al (atomicAdd, 2 contributors max,
// fp32 add commutative -> deterministic) + coalesced bf16 C store.
// ---------------------------------------------------------------------------
template <int NT>   // NT = total N of C (256 or 128); tile is always 128 cols
__global__ __launch_bounds__(256) void gemm_db(
    const unsigned short* __restrict__ A2,   // [M][512] = [hi(256)|lo(256)]
    const unsigned short* __restrict__ B2,   // [NT][512]
    unsigned short* __restrict__ C,          // [M][NT] bf16
    const float* __restrict__ asrc,          // [NT]
    const float* __restrict__ adst,          // [NT]
    float* __restrict__ als,                 // [M] (pre-zeroed; atomicAdd)
    float* __restrict__ ald,                 // [M]
    int M) {
    __shared__ unsigned short sbuf[20480];   // 4 tiles x 128 x 40 shorts = 40KB
    unsigned short* Ah = sbuf;
    unsigned short* Al = sbuf + 5120;
    unsigned short* Bh = sbuf + 10240;
    unsigned short* Bl = sbuf + 15360;

    int tid = threadIdx.x;
    int wave = tid >> 6, lane = tid & 63;
    int wm = wave & 1, wn = wave >> 1;
    int lq = lane >> 4, lm = lane & 15;
    int bm = blockIdx.x * 128;
    int bn = blockIdx.y * 128;

    f32x4 acc[4][4];
#pragma unroll
    for (int i = 0; i < 4; i++)
#pragma unroll
        for (int j = 0; j < 4; j++) {
            acc[i][j][0] = 0.f; acc[i][j][1] = 0.f;
            acc[i][j][2] = 0.f; acc[i][j][3] = 0.f;
        }

    // staging geometry: unit u = p*256+tid (p=0,1): row = u>>2 (0..127),
    // sub = u&3 (16B unit within 32-short chunk row)
    int r0 = tid >> 2, sub = tid & 3;
    int ar0 = min(bm + r0, M - 1), ar1 = min(bm + r0 + 64, M - 1);
    const unsigned short* aSrc0 = A2 + (size_t)ar0 * 512 + sub * 8;
    const unsigned short* aSrc1 = A2 + (size_t)ar1 * 512 + sub * 8;
    const unsigned short* bSrc0 = B2 + (size_t)(bn + r0) * 512 + sub * 8;
    const unsigned short* bSrc1 = B2 + (size_t)(bn + r0 + 64) * 512 + sub * 8;
    int ld0 = r0 * 40 + sub * 8;          // LDS offset (shorts) rows 0..63
    int ld1 = (r0 + 64) * 40 + sub * 8;   // rows 64..127

    uint4 pAh0, pAh1, pAl0, pAl1, pBh0, pBh1, pBl0, pBl1;

    auto loadreg = [&](int c) {
        int o = c * 32;           // hi chunk offset (shorts)
        pAh0 = *(const uint4*)(aSrc0 + o);       pAh1 = *(const uint4*)(aSrc1 + o);
        pAl0 = *(const uint4*)(aSrc0 + 256 + o); pAl1 = *(const uint4*)(aSrc1 + 256 + o);
        pBh0 = *(const uint4*)(bSrc0 + o);       pBh1 = *(const uint4*)(bSrc1 + o);
        pBl0 = *(const uint4*)(bSrc0 + 256 + o); pBl1 = *(const uint4*)(bSrc1 + 256 + o);
    };
    auto writereg = [&]() {
        *(uint4*)(Ah + ld0) = pAh0; *(uint4*)(Ah + ld1) = pAh1;
        *(uint4*)(Al + ld0) = pAl0; *(uint4*)(Al + ld1) = pAl1;
        *(uint4*)(Bh + ld0) = pBh0; *(uint4*)(Bh + ld1) = pBh1;
        *(uint4*)(Bl + ld0) = pBl0; *(uint4*)(Bl + ld1) = pBl1;
    };

    loadreg(0);
#pragma unroll 1
    for (int c = 0; c < 8; c++) {
        __syncthreads();          // prior chunk's ds_reads complete
        writereg();
        __syncthreads();          // staged data visible
        if (c < 7) loadreg(c + 1);  // global loads fly during MFMA below

        // a-fragments hoisted (8 reads), b-fragments streamed (8 reads)
        bf16x8 afh[4], afl[4];
#pragma unroll
        for (int i = 0; i < 4; i++) {
            int row = wm * 64 + i * 16 + lm;
            afh[i] = *(const bf16x8*)(Ah + row * 40 + lq * 8);
            afl[i] = *(const bf16x8*)(Al + row * 40 + lq * 8);
        }
#pragma unroll
        for (int j = 0; j < 4; j++) {
            int row = wn * 64 + j * 16 + lm;
            bf16x8 bh = *(const bf16x8*)(Bh + row * 40 + lq * 8);
            bf16x8 bl = *(const bf16x8*)(Bl + row * 40 + lq * 8);
#pragma unroll
            for (int i = 0; i < 4; i++) {
                acc[i][j] = __builtin_amdgcn_mfma_f32_16x16x32_bf16(afh[i], bh, acc[i][j], 0, 0, 0);
                acc[i][j] = __builtin_amdgcn_mfma_f32_16x16x32_bf16(afl[i], bh, acc[i][j], 0, 0, 0);
                acc[i][j] = __builtin_amdgcn_mfma_f32_16x16x32_bf16(afh[i], bl, acc[i][j], 0, 0, 0);
            }
        }
    }

    __syncthreads();   // all LDS reads done; Cs aliases sbuf

    // Epilogue. C/D layout: col = lane&15, row = (lane>>4)*4 + reg.
    unsigned short* Cs = sbuf;   // [128][136] = 34816 shorts <= 20480? NO -> 17408 shorts, fits
#pragma unroll
    for (int i = 0; i < 4; i++) {
#pragma unroll
        for (int rr = 0; rr < 4; rr++) {
            int row = wm * 64 + i * 16 + lq * 4 + rr;
#pragma unroll
            for (int j = 0; j < 4; j++)
                Cs[row * 136 + wn * 64 + j * 16 + lm] = f2bf_rn(acc[i][j][rr]);
        }
    }
    __syncthreads();

    // fused partial al over this 128-col tile: 2 threads/row
    {
        int r = tid >> 1;
        int cl = (tid & 1) * 64;
        float s = 0.f, d = 0.f;
#pragma unroll
        for (int c8 = 0; c8 < 8; c8++) {
            bf16x8 v8 = *(const bf16x8*)(Cs + r * 136 + cl + c8 * 8);
#pragma unroll
            for (int u = 0; u < 8; u++) {
                float v = bf2f((unsigned short)v8[u]);
                s += v * asrc[bn + cl + c8 * 8 + u];
                d += v * adst[bn + cl + c8 * 8 + u];
            }
        }
        s += __shfl_xor(s, 1); d += __shfl_xor(d, 1);
        if ((tid & 1) == 0 && (bm + r) < M) {
            atomicAdd(&als[bm + r], s);
            atomicAdd(&ald[bm + r], d);
        }
    }

    // coalesced C store: 128 rows x 16 uint4
#pragma unroll
    for (int k = 0; k < 8; k++) {
        int u = k * 256 + tid;
        int row = u >> 4, q = u & 15;
        if (bm + row < M)
            *(uint4*)(C + (size_t)(bm + row) * NT + bn + q * 8) = *(const uint4*)(Cs + row * 136 + q * 8);
    }
}

// ---------------------------------------------------------------------------
// Fused attention softmax + aggregate + bias + relu (bf16 h gather).
// R6-proven linear mapping: one wave per (graph b, dst node n);
// 16-wide load bursts for memory-level parallelism.
// OUTMODE 0: fp32 out.  OUTMODE 1: split-bf16 [M][2F] feeding next GEMM.
// ---------------------------------------------------------------------------
template <int F, int OUTMODE>
__global__ __launch_bounds__(256) void agg_kernel(const unsigned short* __restrict__ h,
                                                  const float* __restrict__ als,
                                                  const float* __restrict__ ald,
                                                  const int* __restrict__ rowstart,
                                                  const int* __restrict__ sorted_src,
                                                  const float* __restrict__ bias,
                                                  float* __restrict__ out,
                                                  unsigned short* __restrict__ out2) {
    constexpr int V = F / 64;
    typedef unsigned short usv __attribute__((ext_vector_type(V)));
    typedef float fvec __attribute__((ext_vector_type(V)));

    int wid = (blockIdx.x * blockDim.x + threadIdx.x) >> 6;  // 0..B*N-1
    int lane = threadIdx.x & 63;
    int b = wid / NN;
    int n = wid - b * NN;

    const float* als_b = als + (size_t)b * NN;
    float aldn = ald[wid];
    int rs = rowstart[n];
    int deg = rowstart[n + 1] - rs;
    const unsigned short* hb = h + (size_t)b * NN * F;

    fvec acc;
#pragma unroll
    for (int u = 0; u < V; u++) acc[u] = 0.f;
    float sum = 0.f;

    for (int c0 = 0; c0 < deg; c0 += 64) {
        int j = c0 + lane;
        float ex = 0.f;
        int srcj = 0;
        if (j < deg) {
            srcj = sorted_src[rs + j];
            float e = als_b[srcj] + aldn;
            e = e > 0.f ? e : 0.2f * e;
            ex = __expf(e);
        }
        sum += ex;
        int cnt = min(64, deg - c0);

        int nfull = cnt >> 4;
        for (int g = 0; g < nfull; g++) {
            int bse = g << 4;
            int s[16]; float w[16];
#pragma unroll
            for (int i = 0; i < 16; i++) {
                s[i] = __shfl(srcj, bse + i);
                w[i] = __shfl(ex, bse + i);
            }
            usv r[16];
#pragma unroll
            for (int i = 0; i < 16; i++)
                r[i] = *(const usv*)(hb + (size_t)s[i] * F + lane * V);
#pragma unroll
            for (int i = 0; i < 16; i++)
#pragma unroll
                for (int u = 0; u < V; u++) acc[u] += w[i] * bf2f(r[i][u]);
        }
        for (int bse = nfull << 4; bse < cnt; bse += 4) {
            int s[4]; float w[4];
#pragma unroll
            for (int i = 0; i < 4; i++) {
                s[i] = __shfl(srcj, bse + i);
                w[i] = __shfl(ex, bse + i);
            }
            usv r[4];
#pragma unroll
            for (int i = 0; i < 4; i++)
                r[i] = *(const usv*)(hb + (size_t)s[i] * F + lane * V);
#pragma unroll
            for (int i = 0; i < 4; i++)
#pragma unroll
                for (int u = 0; u < V; u++) acc[u] += w[i] * bf2f(r[i][u]);
        }
    }
#pragma unroll
    for (int off = 32; off; off >>= 1) sum += __shfl_xor(sum, off);
    float inv = 1.0f / (sum + 1e-16f);

    fvec r;
#pragma unroll
    for (int u = 0; u < V; u++) {
        float v = acc[u] * inv + bias[lane * V + u];
        r[u] = fmaxf(v, 0.f);
    }
    if (OUTMODE == 0) {
        *(fvec*)(out + (size_t)wid * F + lane * V) = r;
    } else {
        ushort4 hi, lo;
        hi.x = f2bf_rn(r[0]); lo.x = f2bf_rn(r[0] - bf2f(hi.x));
        hi.y = f2bf_rn(r[1]); lo.y = f2bf_rn(r[1] - bf2f(hi.y));
        hi.z = f2bf_rn(r[2]); lo.z = f2bf_rn(r[2] - bf2f(hi.z));
        hi.w = f2bf_rn(r[3]); lo.w = f2bf_rn(r[3] - bf2f(hi.w));
        unsigned short* o = out2 + (size_t)wid * 2 * F;
        *(ushort4*)(o + lane * 4) = hi;
        *(ushort4*)(o + F + lane * 4) = lo;
    }
}

// ---------------------------------------------------------------------------
extern "C" void kernel_launch(void* const* d_in, const int* in_sizes, int n_in,
                              void* d_out, int out_size, void* d_ws, size_t ws_size,
                              hipStream_t stream) {
    const float* x     = (const float*)d_in[0];
    const int*   ei    = (const int*)d_in[1];
    const float* W0    = (const float*)d_in[2];
    const float* b0    = (const float*)d_in[3];
    const float* asrc0 = (const float*)d_in[4];
    const float* adst0 = (const float*)d_in[5];
    const float* W1    = (const float*)d_in[6];
    const float* b1    = (const float*)d_in[7];
    const float* asrc1 = (const float*)d_in[8];
    const float* adst1 = (const float*)d_in[9];
    float* outp = (float*)d_out;

    const int M = BB * NN;  // 40000

    size_t off = 0;
    char* base = (char*)d_ws;
    auto alloc = [&](size_t bytes) {
        void* p = base + off;
        off += (bytes + 255) & ~(size_t)255;
        return p;
    };
    int*   deg        = (int*)alloc((size_t)NN * 4);   // deg+fill zeroed in ONE memset
    int*   fill       = (int*)alloc((size_t)NN * 4);
    int*   rowstart   = (int*)alloc((size_t)(NN + 1) * 4);
    int*   sorted_src = (int*)alloc((size_t)ETOT * 4);
    unsigned short* A2  = (unsigned short*)alloc((size_t)M * 512 * 2);  // x-split; reused as out0-split
    unsigned short* W02 = (unsigned short*)alloc((size_t)F1 * 512 * 2);
    unsigned short* W12 = (unsigned short*)alloc((size_t)F2 * 512 * 2);
    unsigned short* h   = (unsigned short*)alloc((size_t)M * F1 * 2);   // bf16 pre-agg features
    float* als        = (float*)alloc((size_t)M * 4);   // als+ald contiguous ->
    float* ald        = (float*)alloc((size_t)M * 4);   // one memset covers both

    hipMemsetAsync(deg, 0, (char*)fill - (char*)deg + (size_t)NN * 4, stream);

    int egrid = (ETOT + 255) / 256;
    count_kernel<<<egrid, 256, 0, stream>>>(ei, deg);
    scan_kernel<<<1, 256, 0, stream>>>(deg, rowstart);
    scatter_kernel<<<egrid, 256, 0, stream>>>(ei, rowstart, fill, sorted_src);

    int wgrid = (M * 64) / 256;            // 10000 blocks, 1 wave per (b,node)

    conv_split<<<(M * (F0 / 4) + 255) / 256, 256, 0, stream>>>(x, A2, M, F0);
    conv_split<<<(F1 * (F0 / 4) + 255) / 256, 256, 0, stream>>>(W0, W02, F1, F0);
    conv_split<<<(F2 * (F1 / 4) + 255) / 256, 256, 0, stream>>>(W1, W12, F2, F1);

    int mtiles = (M + 127) / 128;          // 313

    // ----- layer 0 -----  (al fused into GEMM epilogue via atomicAdd)
    hipMemsetAsync(als, 0, (size_t)2 * M * 4, stream);
    gemm_db<F1><<<dim3(mtiles, F1 / 128), 256, 0, stream>>>(A2, W02, h, asrc0, adst0, als, ald, M);
    agg_kernel<F1, 1><<<wgrid, 256, 0, stream>>>(h, als, ald, rowstart, sorted_src, b0,
                                                 nullptr, A2 /* out0 split */);

    // ----- layer 1 -----
    hipMemsetAsync(als, 0, (size_t)2 * M * 4, stream);
    gemm_db<F2><<<dim3(mtiles, F2 / 128), 256, 0, stream>>>(A2, W12, h, asrc1, adst1, als, ald, M);
    agg_kernel<F2, 0><<<wgrid, 256, 0, stream>>>(h, als, ald, rowstart, sorted_src, b1,
                                                 outp, nullptr);
}